// Round 13
// baseline (426.130 us; speedup 1.0000x reference)
//
#include <hip/hip_runtime.h>

// Linear(int8-weight, block-sparse) -> quantize -> dequantize, as one fp16 MFMA GEMM.
// out[n,o] = dq(q( (x @ (w_q*mask)^T) * w_scale + bias ))
// N=8192 tokens, O=4096, K=4096.
//
// Numerics: w_q*mask integers in [-127,127] exact in fp16 (validated absmax 0.0625).
//
// GEMM round 13: B FROM GLOBAL TO REGISTERS (no B in LDS).
// Rationale (r12 accounting): LDS unit load/tile/CU was 192 ds_read_b128
// (2304cyc) + 64KiB gload-writes (768cyc) = 3072cyc > MFMA 2483cyc -> the
// LDS unit was the binding resource (81% ceiling) regardless of schedule
// (7 schedule variants all pinned at 238-246us). B fragments have a fully
// coalesced global pattern (lane (lr,kq): 16 rows x full 64B lines per
// dwordx4) and B is L2-resident (2MB/bn-column; bn-major block order).
// Removing B from LDS: reads 192->128, writes 64->32KiB -> LDS 1920cyc <
// MFMA 2483 -> matrix-bound for the first time.
//
// Schedule per K-tile t (buf p=t&1), 4 half-phases, 2 barriers:
//  H1: rd a47.kh0(t)@p[4]; ld bv1(t)[4];  VMCNT(6|4); MFMA m03.kh0(a0,bv0); LGKM0; BAR
//  H2: rd a03.kh1(t)@p[4]; stgA kh0(t+2)->p[2];       MFMA m47.kh0(a1,bv0)
//  H3: rd a47.kh1(t)@p[4]; ld bv0(t+1)[4];VMCNT(6|4|0);MFMA m03.kh1(a0,bv1); LGKM0; BAR
//  H4: rd a03.kh0(t+1)@p^1[4]; stgA kh1(t+2)->p[2];   MFMA m47.kh1(a1,bv1)
// vmcnt ledger (newest-first at each wait):
//  H1: [bv1 4][H4(t-1).stgA 2] = 6 -> forces bv0(t) (H3(t-1)) + kh0(t+1)
//      (H2(t-1).stgA) -> BAR publishes for H4's read. Tail t=NT-1: 4.
//  H3: [bv0' 4][H2.stgA 2] = 6 -> forces bv1(t) + kh1(t+1) (H4(t-1).stgA)
//      -> BAR publishes for H2(t+1). Tails: t=NT-2: 4, t=NT-1: 0.
// Pane WAR: kh0(t) readers drain by LGKM0/compiler-lgkm before BAR(H1),
// stage at H2 after it; kh1(t) readers before BAR(H3), stage at H4. ✓
// A swizzle/staging geometry unchanged (0 bank conflicts rounds 2-12).

#define M_TOK 8192
#define O_FEAT 4096
#define K_FEAT 4096

#define BM 256
#define BN 256
#define BK 64
#define NT (K_FEAT / BK)   // 64 K-tiles

// LDS (A only): smem[2][2][BM*32] f16 = 64 KiB; elem strides:
#define S_BUF 16384
#define S_KH  8192

using f16x8 = __attribute__((ext_vector_type(8))) _Float16;
using f32x4 = __attribute__((ext_vector_type(4))) float;

#define BAR()    asm volatile("s_barrier" ::: "memory")
#define LGKM0()  asm volatile("s_waitcnt lgkmcnt(0)" ::: "memory")
#define VMCNT(n) asm volatile("s_waitcnt vmcnt(" #n ")" ::: "memory")
#define SB0()    __builtin_amdgcn_sched_barrier(0)
#define MFMA16(a, b, c) __builtin_amdgcn_mfma_f32_16x16x32_f16((a), (b), (c), 0, 0, 0)

#define NXBLK (M_TOK * K_FEAT / 8 / 256)   // 16384 x-blocks

// ------------- fused fp32->fp16 conversion (x) + mask-fuse (w) ---------
__global__ __launch_bounds__(256) void cvt_kernel(const float* __restrict__ x,
                                                  const float* __restrict__ wq,
                                                  const int* __restrict__ mask,
                                                  _Float16* __restrict__ xf,
                                                  _Float16* __restrict__ wf) {
    const int b = blockIdx.x;
    if (b < NXBLK) {
        size_t i = ((size_t)b * 256 + threadIdx.x) * 8;
        float4 v0 = *reinterpret_cast<const float4*>(x + i);
        float4 v1 = *reinterpret_cast<const float4*>(x + i + 4);
        f16x8 h;
        h[0] = (_Float16)v0.x; h[1] = (_Float16)v0.y;
        h[2] = (_Float16)v0.z; h[3] = (_Float16)v0.w;
        h[4] = (_Float16)v1.x; h[5] = (_Float16)v1.y;
        h[6] = (_Float16)v1.z; h[7] = (_Float16)v1.w;
        *reinterpret_cast<f16x8*>(xf + i) = h;
    } else {
        size_t i = ((size_t)(b - NXBLK) * 256 + threadIdx.x) * 8;
        float4 v0 = *reinterpret_cast<const float4*>(wq + i);
        float4 v1 = *reinterpret_cast<const float4*>(wq + i + 4);
        int2 mv = *reinterpret_cast<const int2*>(mask + i / 4);
        float m0 = mv.x ? 1.0f : 0.0f;
        float m1 = mv.y ? 1.0f : 0.0f;
        f16x8 h;
        h[0] = (_Float16)(v0.x * m0); h[1] = (_Float16)(v0.y * m0);
        h[2] = (_Float16)(v0.z * m0); h[3] = (_Float16)(v0.w * m0);
        h[4] = (_Float16)(v1.x * m1); h[5] = (_Float16)(v1.y * m1);
        h[6] = (_Float16)(v1.z * m1); h[7] = (_Float16)(v1.w * m1);
        *reinterpret_cast<f16x8*>(wf + i) = h;
    }
}

// ---------------- 256x256 fp16 MFMA GEMM, B-from-global -----------------
// A [8192][4096] f16 row-major, B [4096][4096] f16 row-major (B^T GEMM).
__global__ __launch_bounds__(512, 2) void gemm_kernel(const _Float16* __restrict__ A,
                                                      const _Float16* __restrict__ B,
                                                      const float* __restrict__ bias,
                                                      const float* __restrict__ wsp,
                                                      const float* __restrict__ osp,
                                                      float* __restrict__ C) {
    __shared__ __align__(16) _Float16 smem[2][2][BM * 32];   // 64 KiB, A only
    _Float16* sm = &smem[0][0][0];

    const int tid  = threadIdx.x;
    const int lane = tid & 63;
    const int w    = tid >> 6;      // 0..7
    const int wm   = w >> 2;        // 0..1  (M half)
    const int wn   = w & 3;         // 0..3  (N quarter)
    const int lr   = lane & 15;     // fragment row/col
    const int kq   = lane >> 4;     // 0..3  k-granule

    // bn-major: consecutive blocks share bn -> B column (2 MB) hot in L2
    const int bn = blockIdx.x >> 5; // 16 N-tiles
    const int bm = blockIdx.x & 31; // 32 M-tiles

    // ---- A staging geometry (unchanged; linear dst + inv-swizzled src) ----
    const int sr0  = w * 32 + (lane >> 2);
    const int csrc = ((lane & 3) ^ ((lane >> 3) & 3)) * 8;
    const size_t J1 = (size_t)16 * K_FEAT;

    const _Float16* pA0 = A + (size_t)(bm * BM + sr0) * K_FEAT + csrc;  // kh0
    const _Float16* pA1 = pA0 + 32;                                      // kh1

    const int dst0 = (w * 128 + lane) * 8;
    const int dst1 = dst0 + 64 * 8;

    auto stg = [&](const _Float16* src, _Float16* dstp) {
        __builtin_amdgcn_global_load_lds(
            (const __attribute__((address_space(1))) void*)(const void*)src,
            (__attribute__((address_space(3))) void*)(void*)dstp, 16, 0, 0);
    };

    // ---- A fragment read offsets (swizzled; m+4 => +2048, kh1 => +S_KH) ----
    int offA[4];
#pragma unroll
    for (int m = 0; m < 4; ++m) {
        const int r = wm * 128 + m * 16 + lr;
        offA[m] = r * 32 + ((kq ^ ((r >> 1) & 3)) << 3);
    }

    // ---- B per-lane global pointers (one per n-fragment) ----
    // lane (lr,kq) of fragment nf reads B[bn*256+wn*64+nf*16+lr][k .. k+8)
    const _Float16* pBv[4];
#pragma unroll
    for (int nf = 0; nf < 4; ++nf)
        pBv[nf] = B + (size_t)(bn * BN + wn * 64 + nf * 16 + lr) * K_FEAT + kq * 8;

    f32x4 acc[8][4] = {};
    f16x8 a0[4], a1[4], bv0[4], bv1[4];

    // ---- prologue: stage A tiles 0,1; load bv0(0); drain; prime a0 ----
    stg(pA0, sm + dst0);                        stg(pA0 + J1, sm + dst1);
    stg(pA1, sm + S_KH + dst0);                 stg(pA1 + J1, sm + S_KH + dst1);
    stg(pA0 + BK, sm + S_BUF + dst0);           stg(pA0 + BK + J1, sm + S_BUF + dst1);
    stg(pA1 + BK, sm + S_BUF + S_KH + dst0);    stg(pA1 + BK + J1, sm + S_BUF + S_KH + dst1);
#pragma unroll
    for (int nf = 0; nf < 4; ++nf) bv0[nf] = *reinterpret_cast<const f16x8*>(pBv[nf]);
    VMCNT(0);
    BAR();
#pragma unroll
    for (int m = 0; m < 4; ++m) a0[m] = *reinterpret_cast<const f16x8*>(sm + offA[m]);
    pA0 += 2 * BK; pA1 += 2 * BK;   // -> tile 2 (first staged in-loop)

    for (int t = 0; t < NT; ++t) {
        _Float16* bufp = sm + ((t & 1) ? S_BUF : 0);
        const _Float16* bufn = sm + ((t & 1) ? 0 : S_BUF);
        const bool more = (t + 1 < NT);
        const bool stg_ok = (t + 2 < NT);

        // ---- H1: rd a47.kh0; ld bv1(t); wait bv0(t)+kh0(t+1); MFMA m03.kh0 ----
#pragma unroll
        for (int m = 0; m < 4; ++m)
            a1[m] = *reinterpret_cast<const f16x8*>(bufp + offA[m] + 2048);
#pragma unroll
        for (int nf = 0; nf < 4; ++nf)
            bv1[nf] = *reinterpret_cast<const f16x8*>(pBv[nf] + 32);
        if (t == NT - 1) { VMCNT(4); } else { VMCNT(6); }
        SB0();
        __builtin_amdgcn_s_setprio(1);
#pragma unroll
        for (int m = 0; m < 4; ++m)
#pragma unroll
            for (int n = 0; n < 4; ++n)
                acc[m][n] = MFMA16(a0[m], bv0[n], acc[m][n]);
        __builtin_amdgcn_s_setprio(0);
        LGKM0();   // drain a47.kh0 reads (pane re-staged next phase)
        BAR();

        // ---- H2: rd a03.kh1; stgA kh0(t+2)->bufp; MFMA m47.kh0 ----
#pragma unroll
        for (int m = 0; m < 4; ++m)
            a0[m] = *reinterpret_cast<const f16x8*>(bufp + offA[m] + S_KH);
        if (stg_ok) { stg(pA0, bufp + dst0); stg(pA0 + J1, bufp + dst1); }
        SB0();
        __builtin_amdgcn_s_setprio(1);
#pragma unroll
        for (int m = 0; m < 4; ++m)
#pragma unroll
            for (int n = 0; n < 4; ++n)
                acc[4 + m][n] = MFMA16(a1[m], bv0[n], acc[4 + m][n]);
        __builtin_amdgcn_s_setprio(0);

        // ---- H3: rd a47.kh1; ld bv0(t+1); wait bv1(t)+kh1(t+1); MFMA m03.kh1 ----
#pragma unroll
        for (int m = 0; m < 4; ++m)
            a1[m] = *reinterpret_cast<const f16x8*>(bufp + offA[m] + S_KH + 2048);
        if (more) {
#pragma unroll
            for (int nf = 0; nf < 4; ++nf)
                bv0[nf] = *reinterpret_cast<const f16x8*>(pBv[nf] + 64);
        }
        if (stg_ok) { VMCNT(6); } else if (t == NT - 2) { VMCNT(4); } else { VMCNT(0); }
        SB0();
        __builtin_amdgcn_s_setprio(1);
#pragma unroll
        for (int m = 0; m < 4; ++m)
#pragma unroll
            for (int n = 0; n < 4; ++n)
                acc[m][n] = MFMA16(a0[m], bv1[n], acc[m][n]);
        __builtin_amdgcn_s_setprio(0);
        LGKM0();   // drain a47.kh1 reads (pane re-staged next phase)
        BAR();

        // ---- H4: rd a03.kh0(t+1)@bufn; stgA kh1(t+2)->bufp; MFMA m47.kh1 ----
        if (more) {
#pragma unroll
            for (int m = 0; m < 4; ++m)
                a0[m] = *reinterpret_cast<const f16x8*>(bufn + offA[m]);
        }
        if (stg_ok) { stg(pA1, bufp + S_KH + dst0); stg(pA1 + J1, bufp + S_KH + dst1); }
        SB0();
        __builtin_amdgcn_s_setprio(1);
#pragma unroll
        for (int m = 0; m < 4; ++m)
#pragma unroll
            for (int n = 0; n < 4; ++n)
                acc[4 + m][n] = MFMA16(a1[m], bv1[n], acc[4 + m][n]);
        __builtin_amdgcn_s_setprio(0);
        // no barrier: next hazardous op (H2(t+1) stage) sits behind BAR(H1(t+1))

        pA0 += BK; pA1 += BK;
#pragma unroll
        for (int nf = 0; nf < 4; ++nf) pBv[nf] += BK;
    }

    // ---------------- fused epilogue: scale + bias + quant + dequant ----
    const float wscale = wsp[0];
    const float oscale = osp[0];
    const int row0 = bm * BM + wm * 128;
    const int col0 = bn * BN + wn * 64;
#pragma unroll
    for (int n = 0; n < 4; ++n) {
        const int col = col0 + n * 16 + lr;
        const float bc = bias[col];
#pragma unroll
        for (int m = 0; m < 8; ++m) {
#pragma unroll
            for (int j = 0; j < 4; ++j) {
                const int row = row0 + m * 16 + kq * 4 + j;
                float y = acc[m][n][j] * wscale + bc;
                float q = rintf(y / oscale);          // round-half-even, matches jnp.round
                q = fminf(fmaxf(q, -128.0f), 127.0f);
                C[(size_t)row * O_FEAT + col] = q * oscale;
            }
        }
    }
}

extern "C" void kernel_launch(void* const* d_in, const int* in_sizes, int n_in,
                              void* d_out, int out_size, void* d_ws, size_t ws_size,
                              hipStream_t stream) {
    const float* x        = (const float*)d_in[0];  // [8192,4096] fp32
    const float* wq       = (const float*)d_in[1];  // [4096,4096] fp32 (int8 values)
    const float* bias     = (const float*)d_in[2];  // [4096]
    const float* w_scale  = (const float*)d_in[3];  // scalar
    const float* out_scale= (const float*)d_in[4];  // scalar
    const int*   mask     = (const int*)d_in[5];    // [4096,1024] int32
    float* out = (float*)d_out;

    _Float16* xf = (_Float16*)d_ws;                                        // 64 MiB
    _Float16* wf = (_Float16*)((char*)d_ws + (size_t)M_TOK * K_FEAT * 2);  // +32 MiB

    // fused cvt: 16384 x-blocks + 8192 w-blocks
    cvt_kernel<<<NXBLK + (O_FEAT * K_FEAT / 8 / 256), 256, 0, stream>>>(x, wq, mask, xf, wf);

    // (8192/256) x (4096/256) = 32*16 = 512 blocks, 512 threads
    gemm_kernel<<<dim3((M_TOK / BM) * (O_FEAT / BN)), 512, 0, stream>>>(
        xf, wf, bias, w_scale, out_scale, out);
}

// Round 14
// 295.377 us; speedup vs baseline: 1.4427x; 1.4427x over previous
//
#include <hip/hip_runtime.h>

// Linear(int8-weight, block-sparse) -> quantize -> dequantize, as one fp16 MFMA GEMM.
// out[n,o] = dq(q( (x @ (w_q*mask)^T) * w_scale + bias ))
// N=8192 tokens, O=4096, K=4096.
//
// Numerics: w_q*mask integers in [-127,127] exact in fp16 (validated absmax 0.0625).
//
// GEMM: r12 balanced 4-phase pipeline (best measured: 238.6us, MfmaUtil 54.6,
// 0 bank conflicts) + XCD-AWARE BLOCK SWIZZLE (the only change):
// XCD k = blockIdx&7 owns bm-slab [4k,4k+4) x all bn (512%8==0 -> bijective).
// ~32 concurrent blocks/XCD span 2 A-panels = 4MB ~= one XCD L2, so A
// staging hits L2 (~200cyc) instead of L3 (~400-600) -> smaller vmcnt
// residual at the publish points.
// r13's B-from-global REVERTED: direct-to-VGPR loads put L2 latency inside
// the MFMA register dataflow with ~1 half-phase cover -> 28% util. LDS
// staging (gload_lds + counted vmcnt + barrier) is the latency decoupler.
//
// Schedule per K-tile (unchanged from r12):
//   P1: rd a47_k0+b1v01(6); stg B_k0(s+2)->sb; MFMA m03.kh0; LGKM0; BAR
//   P2: rd a03_k1+b1v23(6); stg A_k0(s+2)->sb; MFMA m47.kh0; LGKM0; VMCNT(4|0); BAR
//   P3: rd a47_k1+b0v01'(6); stg B_k1(s+2)->sb; MFMA m03.kh1; LGKM0; BAR
//   P4: rd a03_k0'+b0v23'(6); stg A_k1(s+2)->sb; MFMA m47.kh1; LGKM0; BAR

#define M_TOK 8192
#define O_FEAT 4096
#define K_FEAT 4096

#define BM 256
#define BN 256
#define BK 64
#define NT (K_FEAT / BK)   // 64 K-tiles

// LDS element strides for smem[2][2][2][BM*32]: buf=32768, mat=16384, kh=8192
#define S_BUF 32768
#define S_MAT 16384
#define S_KH  8192

using f16x8 = __attribute__((ext_vector_type(8))) _Float16;
using f32x4 = __attribute__((ext_vector_type(4))) float;

#define BAR()    asm volatile("s_barrier" ::: "memory")
#define LGKM0()  asm volatile("s_waitcnt lgkmcnt(0)" ::: "memory")
#define VMCNT(n) asm volatile("s_waitcnt vmcnt(" #n ")" ::: "memory")
#define SB0()    __builtin_amdgcn_sched_barrier(0)
#define MFMA16(a, b, c) __builtin_amdgcn_mfma_f32_16x16x32_f16((a), (b), (c), 0, 0, 0)

#define NXBLK (M_TOK * K_FEAT / 8 / 256)   // 16384 x-blocks

// ------------- fused fp32->fp16 conversion (x) + mask-fuse (w) ---------
__global__ __launch_bounds__(256) void cvt_kernel(const float* __restrict__ x,
                                                  const float* __restrict__ wq,
                                                  const int* __restrict__ mask,
                                                  _Float16* __restrict__ xf,
                                                  _Float16* __restrict__ wf) {
    const int b = blockIdx.x;
    if (b < NXBLK) {
        size_t i = ((size_t)b * 256 + threadIdx.x) * 8;
        float4 v0 = *reinterpret_cast<const float4*>(x + i);
        float4 v1 = *reinterpret_cast<const float4*>(x + i + 4);
        f16x8 h;
        h[0] = (_Float16)v0.x; h[1] = (_Float16)v0.y;
        h[2] = (_Float16)v0.z; h[3] = (_Float16)v0.w;
        h[4] = (_Float16)v1.x; h[5] = (_Float16)v1.y;
        h[6] = (_Float16)v1.z; h[7] = (_Float16)v1.w;
        *reinterpret_cast<f16x8*>(xf + i) = h;
    } else {
        size_t i = ((size_t)(b - NXBLK) * 256 + threadIdx.x) * 8;
        float4 v0 = *reinterpret_cast<const float4*>(wq + i);
        float4 v1 = *reinterpret_cast<const float4*>(wq + i + 4);
        int2 mv = *reinterpret_cast<const int2*>(mask + i / 4);
        float m0 = mv.x ? 1.0f : 0.0f;
        float m1 = mv.y ? 1.0f : 0.0f;
        f16x8 h;
        h[0] = (_Float16)(v0.x * m0); h[1] = (_Float16)(v0.y * m0);
        h[2] = (_Float16)(v0.z * m0); h[3] = (_Float16)(v0.w * m0);
        h[4] = (_Float16)(v1.x * m1); h[5] = (_Float16)(v1.y * m1);
        h[6] = (_Float16)(v1.z * m1); h[7] = (_Float16)(v1.w * m1);
        *reinterpret_cast<f16x8*>(wf + i) = h;
    }
}

// ---------------- 256x256 balanced 4-phase fp16 MFMA GEMM ---------------
// A [8192][4096] f16 row-major, B [4096][4096] f16 row-major (B^T GEMM).
// Swizzle: 16B granule kq -> kq ^ ((row>>1)&3); linear LDS dest +
// inverse-permuted global src (global_load_lds), same XOR on ds_read.
__global__ __launch_bounds__(512, 2) void gemm_kernel(const _Float16* __restrict__ A,
                                                      const _Float16* __restrict__ B,
                                                      const float* __restrict__ bias,
                                                      const float* __restrict__ wsp,
                                                      const float* __restrict__ osp,
                                                      float* __restrict__ C) {
    __shared__ __align__(16) _Float16 smem[2][2][2][BM * 32];
    _Float16* sm = &smem[0][0][0][0];

    const int tid  = threadIdx.x;
    const int lane = tid & 63;
    const int w    = tid >> 6;      // 0..7
    const int wm   = w >> 2;        // 0..1  (M half)
    const int wn   = w & 3;         // 0..3  (N quarter)
    const int lr   = lane & 15;     // fragment row/col
    const int kq   = lane >> 4;     // 0..3  k-granule

    // XCD-aware swizzle: XCD k (= blockIdx&7, round-robin dispatch) owns
    // bm-slab [4k, 4k+4) x all 16 bn. 512 % 8 == 0 -> bijective.
    const int xcd = blockIdx.x & 7;
    const int idx = blockIdx.x >> 3;      // 0..63 within slab
    const int bm  = xcd * 4 + (idx >> 4); // 32 M-tiles
    const int bn  = idx & 15;             // 16 N-tiles

    // ---- staging geometry (hoisted advancing pointers) ----
    const int sr0  = w * 32 + (lane >> 2);
    const int csrc = ((lane & 3) ^ ((lane >> 3) & 3)) * 8;  // inverse-swizzled src granule
    const size_t J1 = (size_t)16 * K_FEAT;                  // j=1 source row offset

    const _Float16* pA0 = A + (size_t)(bm * BM + sr0) * K_FEAT + csrc;  // A kh0
    const _Float16* pA1 = pA0 + 32;                                      // A kh1
    const _Float16* pB0 = B + (size_t)(bn * BN + sr0) * K_FEAT + csrc;  // B kh0
    const _Float16* pB1 = pB0 + 32;                                      // B kh1

    const int dst0 = (w * 128 + lane) * 8;   // j=0 LDS dst elem offset within a pane
    const int dst1 = dst0 + 64 * 8;          // j=1

    auto stg = [&](const _Float16* src, const _Float16* dstp) {
        __builtin_amdgcn_global_load_lds(
            (const __attribute__((address_space(1))) void*)(const void*)src,
            (__attribute__((address_space(3))) void*)(void*)(_Float16*)(uintptr_t)dstp,
            16, 0, 0);
    };

    // ---- fragment read offsets (hoisted, swizzled) ----
    int offA[4], offB[4];
#pragma unroll
    for (int m = 0; m < 4; ++m) {
        const int r = wm * 128 + m * 16 + lr;
        offA[m] = r * 32 + ((kq ^ ((r >> 1) & 3)) << 3);
    }
#pragma unroll
    for (int n = 0; n < 4; ++n) {
        const int r = wn * 64 + n * 16 + lr;
        offB[n] = r * 32 + ((kq ^ ((r >> 1) & 3)) << 3);
    }
    auto rd = [&](const _Float16* sbuf, int off, int immE) -> f16x8 {
        return *reinterpret_cast<const f16x8*>(sbuf + off + immE);  // immE folds into ds offset
    };

    f32x4 acc[8][4] = {};
    f16x8 a0[4], a1[4], b0v[4], b1v[4];

    // ---- prologue: stage tile0->buf0, tile1->buf1 (16 loads) ----
    stg(pA0, sm + dst0);                 stg(pA0 + J1, sm + dst1);
    stg(pB0, sm + S_MAT + dst0);         stg(pB0 + J1, sm + S_MAT + dst1);
    stg(pA1, sm + S_KH + dst0);          stg(pA1 + J1, sm + S_KH + dst1);
    stg(pB1, sm + S_MAT + S_KH + dst0);  stg(pB1 + J1, sm + S_MAT + S_KH + dst1);
    pA0 += BK; pA1 += BK; pB0 += BK; pB1 += BK;   // -> tile 1
    stg(pA0, sm + S_BUF + dst0);                 stg(pA0 + J1, sm + S_BUF + dst1);
    stg(pB0, sm + S_BUF + S_MAT + dst0);         stg(pB0 + J1, sm + S_BUF + S_MAT + dst1);
    stg(pA1, sm + S_BUF + S_KH + dst0);          stg(pA1 + J1, sm + S_BUF + S_KH + dst1);
    stg(pB1, sm + S_BUF + S_MAT + S_KH + dst0);  stg(pB1 + J1, sm + S_BUF + S_MAT + S_KH + dst1);
    pA0 += BK; pA1 += BK; pB0 += BK; pB1 += BK;   // -> tile 2 (first staged in-loop)
    VMCNT(8);   // tile0 landed; tile1 in flight
    BAR();
    // prime P1(0) operands from buf0, then drain+barrier (P1/P2(0) stages
    // overwrite buf0.B_k0 / buf0.A_k0 -- the panes these reads touch)
#pragma unroll
    for (int m = 0; m < 4; ++m) a0[m] = rd(sm, offA[m], 0);
#pragma unroll
    for (int n = 0; n < 4; ++n) b0v[n] = rd(sm, offB[n], S_MAT);
    LGKM0();
    BAR();

    for (int s = 0; s < NT; ++s) {
        const _Float16* sb = sm + ((s & 1) ? S_BUF : 0);   // current buf
        const _Float16* sn = sm + ((s & 1) ? 0 : S_BUF);   // next buf
        const bool more = (s + 1 < NT);
        const bool stg_ok = (s + 2 < NT);

        // ---- P1: rd a47_k0 + b1v01 (6); stg B_k0(s+2)->sb; MFMA m03.kh0 ----
#pragma unroll
        for (int m = 0; m < 4; ++m) a1[m] = rd(sb, offA[m], 2048);
        b1v[0] = rd(sb, offB[0], S_MAT + S_KH);
        b1v[1] = rd(sb, offB[1], S_MAT + S_KH);
        if (stg_ok) { stg(pB0, sb + S_MAT + dst0); stg(pB0 + J1, sb + S_MAT + dst1); }
        SB0();
        __builtin_amdgcn_s_setprio(1);
#pragma unroll
        for (int m = 0; m < 4; ++m)
#pragma unroll
            for (int n = 0; n < 4; ++n)
                acc[m][n] = MFMA16(a0[m], b0v[n], acc[m][n]);
        __builtin_amdgcn_s_setprio(0);
        SB0(); LGKM0();   // own reads ran under the MFMA; drain for WAR
        BAR();

        // ---- P2: rd a03_k1 + b1v23 (6); stg A_k0(s+2)->sb; MFMA m47.kh0; publish ----
#pragma unroll
        for (int m = 0; m < 4; ++m) a0[m] = rd(sb, offA[m], S_KH);
        b1v[2] = rd(sb, offB[2], S_MAT + S_KH);
        b1v[3] = rd(sb, offB[3], S_MAT + S_KH);
        if (stg_ok) { stg(pA0, sb + dst0); stg(pA0 + J1, sb + dst1); }
        SB0();
        __builtin_amdgcn_s_setprio(1);
#pragma unroll
        for (int m = 0; m < 4; ++m)
#pragma unroll
            for (int n = 0; n < 4; ++n)
                acc[4 + m][n] = MFMA16(a1[m], b0v[n], acc[4 + m][n]);
        __builtin_amdgcn_s_setprio(0);
        SB0(); LGKM0();
        // publish buf(s+1): everything staged through P4(s-1) landed;
        // P1,P2(s) stages (4 loads) may stay in flight. Tail: drain all.
        if (s >= NT - 2) { VMCNT(0); } else { VMCNT(4); }
        BAR();

        // ---- P3: rd a47_k1 + b0v01'(sn) (6); stg B_k1(s+2)->sb; MFMA m03.kh1 ----
#pragma unroll
        for (int m = 0; m < 4; ++m) a1[m] = rd(sb, offA[m], S_KH + 2048);
        if (more) {
            b0v[0] = rd(sn, offB[0], S_MAT);
            b0v[1] = rd(sn, offB[1], S_MAT);
        }
        if (stg_ok) { stg(pB1, sb + S_MAT + S_KH + dst0); stg(pB1 + J1, sb + S_MAT + S_KH + dst1); }
        SB0();
        __builtin_amdgcn_s_setprio(1);
#pragma unroll
        for (int m = 0; m < 4; ++m)
#pragma unroll
            for (int n = 0; n < 4; ++n)
                acc[m][n] = MFMA16(a0[m], b1v[n], acc[m][n]);
        __builtin_amdgcn_s_setprio(0);
        SB0(); LGKM0();
        BAR();

        // ---- P4: rd a03_k0'(sn) + b0v23'(sn) (6); stg A_k1(s+2)->sb; MFMA m47.kh1 ----
        if (more) {
#pragma unroll
            for (int m = 0; m < 4; ++m) a0[m] = rd(sn, offA[m], 0);
            b0v[2] = rd(sn, offB[2], S_MAT);
            b0v[3] = rd(sn, offB[3], S_MAT);
        }
        if (stg_ok) {
            stg(pA1, sb + S_KH + dst0); stg(pA1 + J1, sb + S_KH + dst1);
        }
        SB0();
        __builtin_amdgcn_s_setprio(1);
#pragma unroll
        for (int m = 0; m < 4; ++m)
#pragma unroll
            for (int n = 0; n < 4; ++n)
                acc[4 + m][n] = MFMA16(a1[m], b1v[n], acc[4 + m][n]);
        __builtin_amdgcn_s_setprio(0);
        SB0(); LGKM0();
        BAR();

        pA0 += BK; pA1 += BK; pB0 += BK; pB1 += BK;
    }

    // ---------------- fused epilogue: scale + bias + quant + dequant ----
    const float wscale = wsp[0];
    const float oscale = osp[0];
    const int row0 = bm * BM + wm * 128;
    const int col0 = bn * BN + wn * 64;
#pragma unroll
    for (int n = 0; n < 4; ++n) {
        const int col = col0 + n * 16 + lr;
        const float bc = bias[col];
#pragma unroll
        for (int m = 0; m < 8; ++m) {
#pragma unroll
            for (int j = 0; j < 4; ++j) {
                const int row = row0 + m * 16 + kq * 4 + j;
                float y = acc[m][n][j] * wscale + bc;
                float q = rintf(y / oscale);          // round-half-even, matches jnp.round
                q = fminf(fmaxf(q, -128.0f), 127.0f);
                C[(size_t)row * O_FEAT + col] = q * oscale;
            }
        }
    }
}

extern "C" void kernel_launch(void* const* d_in, const int* in_sizes, int n_in,
                              void* d_out, int out_size, void* d_ws, size_t ws_size,
                              hipStream_t stream) {
    const float* x        = (const float*)d_in[0];  // [8192,4096] fp32
    const float* wq       = (const float*)d_in[1];  // [4096,4096] fp32 (int8 values)
    const float* bias     = (const float*)d_in[2];  // [4096]
    const float* w_scale  = (const float*)d_in[3];  // scalar
    const float* out_scale= (const float*)d_in[4];  // scalar
    const int*   mask     = (const int*)d_in[5];    // [4096,1024] int32
    float* out = (float*)d_out;

    _Float16* xf = (_Float16*)d_ws;                                        // 64 MiB
    _Float16* wf = (_Float16*)((char*)d_ws + (size_t)M_TOK * K_FEAT * 2);  // +32 MiB

    // fused cvt: 16384 x-blocks + 8192 w-blocks
    cvt_kernel<<<NXBLK + (O_FEAT * K_FEAT / 8 / 256), 256, 0, stream>>>(x, wq, mask, xf, wf);

    // (8192/256) x (4096/256) = 32*16 = 512 blocks, 512 threads
    gemm_kernel<<<dim3((M_TOK / BM) * (O_FEAT / BN)), 512, 0, stream>>>(
        xf, wf, bias, w_scale, out_scale, out);
}